// Round 16
// baseline (551.099 us; speedup 1.0000x reference)
//
#include <hip/hip_runtime.h>
#include <math.h>

#define TPB 256
#define TOPK 30
#define NGRAPH 128
#define TKCAP 4096
#define BSHIFT 11
#define NBMAX 128
#define FSHIFT 8
#define NFMAX 800
#define FCAP 4608

// ---------------- CSR build (bucket-based; packed single-int scratch) ----------------
// coarse packed: (src << 11) | (dst & 2047)   [29 bits]
// fine packed:   (src << 8)  | (dst & 255)    [26 bits]

// bhist fused with graph_start (independent work, saves a launch)
__global__ void bhist_gs(const int* __restrict__ src, const int* __restrict__ dst,
                         int* __restrict__ btot, int E, int EB,
                         const int* __restrict__ batch, int* __restrict__ gstart,
                         int n, int B) {
    int blk = blockIdx.x;
    if (blk >= EB) {
        int i = (blk - EB) * blockDim.x + threadIdx.x;
        if (i >= n) return;
        int b = batch[i];
        int bp = (i == 0) ? -1 : batch[i - 1];
        for (int g = bp + 1; g <= b; ++g) gstart[g] = i;
        if (i == n - 1) {
            for (int g = b + 1; g <= B; ++g) gstart[g] = n;
        }
        return;
    }
    __shared__ int bcnt[NBMAX];
    int t = threadIdx.x;
    int base = blk * 2048;
    int lim = E - base; if (lim > 2048) lim = 2048;
    for (int i = t; i < NBMAX; i += 256) bcnt[i] = 0;
    __syncthreads();
    for (int i = t; i < lim; i += 256) {
        int s = src[base + i], d = dst[base + i];
        if (s != d) atomicAdd(&bcnt[d >> BSHIFT], 1);
    }
    __syncthreads();
    for (int i = t; i < NBMAX; i += 256)
        if (bcnt[i] > 0) atomicAdd(&btot[i], bcnt[i]);
}

__global__ void bucket_scan(const int* __restrict__ btot, int* __restrict__ bbase,
                            int nbuckets) {
    __shared__ int ls[NBMAX];
    int t = threadIdx.x;
    int v = (t < nbuckets) ? btot[t] : 0;
    ls[t] = v;
    __syncthreads();
    for (int o = 1; o < NBMAX; o <<= 1) {
        int x = 0;
        if (t >= o) x = ls[t - o];
        __syncthreads();
        ls[t] += x;
        __syncthreads();
    }
    if (t < nbuckets) bbase[t] = ls[t] - v;
}

__global__ void bin_edges(const int* __restrict__ src, const int* __restrict__ dst,
                          const int* __restrict__ bbase_g, int* __restrict__ gcur,
                          int* __restrict__ scratch, int E) {
    __shared__ int eds[2048];
    __shared__ unsigned char ebk[2048];
    __shared__ int bcnt[NBMAX], bbase[NBMAX], boff[NBMAX];
    int t = threadIdx.x;
    int base = blockIdx.x * 2048;
    int lim = E - base; if (lim > 2048) lim = 2048;
    for (int i = t; i < NBMAX; i += 256) { bcnt[i] = 0; boff[i] = 0; }
    __syncthreads();
    for (int i = t; i < lim; i += 256) {
        int s = src[base + i], d = dst[base + i];
        if (s == d) { ebk[i] = 255; }
        else {
            int b = d >> BSHIFT;
            ebk[i] = (unsigned char)b;
            eds[i] = (s << BSHIFT) | (d & ((1 << BSHIFT) - 1));
            atomicAdd(&bcnt[b], 1);
        }
    }
    __syncthreads();
    for (int i = t; i < NBMAX; i += 256) {
        if (bcnt[i] > 0)
            bbase[i] = bbase_g[i] + atomicAdd(&gcur[i], bcnt[i]);
    }
    __syncthreads();
    for (int i = t; i < lim; i += 256) {
        if (ebk[i] != 255) {
            int b = ebk[i];
            int pos = bbase[b] + atomicAdd(&boff[b], 1);
            scratch[pos] = eds[i];
        }
    }
}

// per-node hist over the bucket span -> dinv/snorm AND rowptr (LDS blocked scan).
__global__ void bucket_count(const int* __restrict__ scratch,
                             const int* __restrict__ bbase, const int* __restrict__ btot,
                             int* __restrict__ rowptr, float* __restrict__ dinv,
                             float* __restrict__ snorm, int N, int NB) {
    __shared__ int hist[1 << BSHIFT];
    __shared__ int ls2[256];
    int b = blockIdx.x, t = threadIdx.x;
    int nlo = b << BSHIFT;
    int nn = N - nlo; if (nn > (1 << BSHIFT)) nn = 1 << BSHIFT;
    for (int i = t; i < (1 << BSHIFT); i += 256) hist[i] = 0;
    __syncthreads();
    int lo = bbase[b], hi = lo + btot[b];
    for (int e = lo + t; e < hi; e += 256)
        atomicAdd(&hist[scratch[e] & ((1 << BSHIFT) - 1)], 1);
    __syncthreads();
    int loc[8]; int run = 0;
    #pragma unroll
    for (int j = 0; j < 8; ++j) { loc[j] = run; run += hist[t * 8 + j]; }
    ls2[t] = run;
    __syncthreads();
    for (int o = 1; o < 256; o <<= 1) {
        int x = (t >= o) ? ls2[t - o] : 0;
        __syncthreads();
        ls2[t] += x;
        __syncthreads();
    }
    int base = bbase[b] + ls2[t] - run;
    #pragma unroll
    for (int j = 0; j < 8; ++j) {
        int i = t * 8 + j;
        if (i < nn) {
            rowptr[nlo + i] = base + loc[j];
            int c = hist[i];
            float deg = (float)c + 1.0f;
            dinv[nlo + i] = 1.0f / sqrtf(deg);
            snorm[nlo + i] = 1.0f / deg;
        }
    }
    if (b == NB - 1 && t == 0) rowptr[N] = bbase[b] + btot[b];
}

// re-bin coarse-major scratch -> fine-major scratch2 (both packed single int).
// coarse bucket of a global index found by binary search over bbase (LDS).
__global__ void bin2(const int* __restrict__ scratch, const int* __restrict__ bbase_g,
                     const int* __restrict__ rowptr,
                     int* __restrict__ fcur, int* __restrict__ scratch2, int N, int NB) {
    __shared__ int fcnt[NFMAX], fbase[NFMAX], foff[NFMAX];
    __shared__ int bb[NBMAX];
    __shared__ unsigned short fid[8192];
    int t = threadIdx.x;
    int En = rowptr[N];
    int base = blockIdx.x * 8192;
    if (base >= En) return;
    int lim = En - base; if (lim > 8192) lim = 8192;
    for (int i = t; i < NBMAX; i += 256) bb[i] = (i < NB) ? bbase_g[i] : 0x7fffffff;
    for (int i = t; i < NFMAX; i += 256) { fcnt[i] = 0; foff[i] = 0; }
    __syncthreads();
    for (int i = t; i < lim; i += 256) {
        int gi = base + i;
        int lo = 0, hi = NB - 1;
        while (lo < hi) { int m = (lo + hi + 1) >> 1; if (bb[m] <= gi) lo = m; else hi = m - 1; }
        int e = scratch[gi];
        int fi = (lo << (BSHIFT - FSHIFT)) | ((e >> FSHIFT) & ((1 << (BSHIFT - FSHIFT)) - 1));
        fid[i] = (unsigned short)fi;
        atomicAdd(&fcnt[fi], 1);
    }
    __syncthreads();
    for (int fi = t; fi < NFMAX; fi += 256) {
        if (fcnt[fi] > 0)
            fbase[fi] = rowptr[fi << FSHIFT] + atomicAdd(&fcur[fi], fcnt[fi]);
    }
    __syncthreads();
    for (int i = t; i < lim; i += 256) {
        int e = scratch[base + i];
        int fi = fid[i];
        int pf = ((e >> BSHIFT) << FSHIFT) | (e & ((1 << FSHIFT) - 1));
        int pos = fbase[fi] + atomicAdd(&foff[fi], 1);
        scratch2[pos] = pf;
    }
}

// per fine bucket: LDS counting sort of its own span -> fully coalesced eprec writes.
__global__ __launch_bounds__(256) void scatter_sort(const int* __restrict__ scratch2,
                                                    const int* __restrict__ rowptr,
                                                    const float* __restrict__ dinv,
                                                    int2* __restrict__ eprec, int N) {
    __shared__ int pA[FCAP], inv[FCAP];
    __shared__ int hist[1 << FSHIFT];
    __shared__ int hcur[1 << FSHIFT];
    int f = blockIdx.x, t = threadIdx.x;
    int nlo = f << FSHIFT;
    int nhi = nlo + (1 << FSHIFT); if (nhi > N) nhi = N;
    int lo = rowptr[nlo], hi = rowptr[nhi];
    int span = hi - lo;
    hist[t] = 0;
    __syncthreads();
    if (span <= FCAP) {
        for (int i = t; i < span; i += 256) {
            int e = scratch2[lo + i];
            pA[i] = e;
            atomicAdd(&hist[e & 255], 1);
        }
        __syncthreads();
        int v = hist[t];
        hcur[t] = v;
        __syncthreads();
        for (int o = 1; o < 256; o <<= 1) {
            int x = (t >= o) ? hcur[t - o] : 0;
            __syncthreads();
            hcur[t] += x;
            __syncthreads();
        }
        int excl = hcur[t] - v;
        __syncthreads();
        hcur[t] = excl;
        __syncthreads();
        for (int i = t; i < span; i += 256) {
            int slot = atomicAdd(&hcur[pA[i] & 255], 1);
            inv[slot] = i;
        }
        __syncthreads();
        for (int p = t; p < span; p += 256) {
            int e = pA[inv[p]];
            int s = e >> FSHIFT, d = nlo | (e & 255);
            eprec[lo + p] = make_int2(s, __float_as_int(dinv[s] * dinv[d]));
        }
    } else {
        // fallback (span > FCAP, ~never): direct scatter via LDS cursors
        for (int e0 = lo + t; e0 < hi; e0 += 256) {
            int e = scratch2[e0];
            int s = e >> FSHIFT, d = nlo | (e & 255);
            int p = rowptr[d] + atomicAdd(&hist[e & 255], 1);
            eprec[p] = make_int2(s, __float_as_int(dinv[s] * dinv[d]));
        }
    }
}

// ---------------- GEMMs (register-tiled: 4 cols/thread, b128 LDS reads) ----------------

__global__ void mm_128_32(const float* __restrict__ X, const float* __restrict__ W,
                          float* __restrict__ H, int n) {
    __shared__ float Ws[128 * 32];
    __shared__ float xs[32 * 128];
    int t = threadIdx.x;
    int rbase = blockIdx.x * 32;
    #pragma unroll
    for (int j = 0; j < 4; ++j) {
        int idx = t + 256 * j;
        *(float4*)(Ws + idx * 4) = *(const float4*)(W + idx * 4);
        int row = rbase + (idx >> 5);
        float4 v = make_float4(0.f, 0.f, 0.f, 0.f);
        if (row < n) v = *(const float4*)(X + (long)rbase * 128 + idx * 4);
        *(float4*)(xs + idx * 4) = v;
    }
    __syncthreads();
    int c4 = (t & 7) * 4, r = t >> 3;
    int row = rbase + r;
    if (row >= n) return;
    float ac0 = 0.f, ac1 = 0.f, ac2 = 0.f, ac3 = 0.f;
    #pragma unroll 8
    for (int k0 = 0; k0 < 128; k0 += 4) {
        float4 xv = *(const float4*)(xs + r * 128 + k0);
        #pragma unroll
        for (int j = 0; j < 4; ++j) {
            float xj = (j == 0) ? xv.x : (j == 1) ? xv.y : (j == 2) ? xv.z : xv.w;
            float4 wv = *(const float4*)(Ws + (k0 + j) * 32 + c4);
            ac0 += xj * wv.x; ac1 += xj * wv.y; ac2 += xj * wv.z; ac3 += xj * wv.w;
        }
    }
    *(float4*)(H + (long)row * 32 + c4) = make_float4(ac0, ac1, ac2, ac3);
}

__global__ void mm_32_32(const float* __restrict__ X, const float* __restrict__ W,
                         float* __restrict__ H, int n) {
    __shared__ float Ws[32 * 32];
    __shared__ float xs[32 * 32];
    int t = threadIdx.x;
    int rbase = blockIdx.x * 32;
    {
        *(float4*)(Ws + t * 4) = *(const float4*)(W + t * 4);
        int row = rbase + (t >> 3);
        float4 v = make_float4(0.f, 0.f, 0.f, 0.f);
        if (row < n) v = *(const float4*)(X + (long)rbase * 32 + t * 4);
        *(float4*)(xs + t * 4) = v;
    }
    __syncthreads();
    int c4 = (t & 7) * 4, r = t >> 3;
    int row = rbase + r;
    if (row >= n) return;
    float ac0 = 0.f, ac1 = 0.f, ac2 = 0.f, ac3 = 0.f;
    #pragma unroll
    for (int k0 = 0; k0 < 32; k0 += 4) {
        float4 xv = *(const float4*)(xs + r * 32 + k0);
        #pragma unroll
        for (int j = 0; j < 4; ++j) {
            float xj = (j == 0) ? xv.x : (j == 1) ? xv.y : (j == 2) ? xv.z : xv.w;
            float4 wv = *(const float4*)(Ws + (k0 + j) * 32 + c4);
            ac0 += xj * wv.x; ac1 += xj * wv.y; ac2 += xj * wv.z; ac3 += xj * wv.w;
        }
    }
    *(float4*)(H + (long)row * 32 + c4) = make_float4(ac0, ac1, ac2, ac3);
}

__global__ void mm_32_1(const float* __restrict__ X, const float* __restrict__ W,
                        float* __restrict__ H4, int n) {
    int gid = blockIdx.x * blockDim.x + threadIdx.x;
    int node = gid >> 3, l = gid & 7;
    if (node >= n) return;
    float4 v = *(const float4*)(X + (long)node * 32 + l * 4);
    float s = v.x * W[l * 4] + v.y * W[l * 4 + 1] + v.z * W[l * 4 + 2] + v.w * W[l * 4 + 3];
    s += __shfl_xor(s, 1, 64);
    s += __shfl_xor(s, 2, 64);
    s += __shfl_xor(s, 4, 64);
    if (l == 0) H4[node] = s;
}

// ---------------- edge aggregation (gather, 16-deep MLP) ----------------

__global__ void agg32(const float* __restrict__ H, const int2* __restrict__ eprec,
                      const int* __restrict__ rowptr,
                      const float* __restrict__ snorm, const float* __restrict__ bias,
                      float* __restrict__ OUT, int n) {
    int gid = blockIdx.x * blockDim.x + threadIdx.x;
    int node = gid >> 3, l = gid & 7;
    if (node >= n) return;
    int beg = rowptr[node], end = rowptr[node + 1];
    float ax = 0.f, ay = 0.f, az = 0.f, aw = 0.f;
    int e0 = beg;
    // 16-edge batches: 16 independent line-gathers in flight
    for (; e0 + 16 <= end; e0 += 16) {
        int2 ed0 = eprec[e0 + l];
        int2 ed1 = eprec[e0 + 8 + l];
        int ss[16]; float ww[16];
        #pragma unroll
        for (int j = 0; j < 8; ++j) {
            ss[j] = __shfl(ed0.x, j, 8);
            ww[j] = __shfl(__int_as_float(ed0.y), j, 8);
            ss[8 + j] = __shfl(ed1.x, j, 8);
            ww[8 + j] = __shfl(__int_as_float(ed1.y), j, 8);
        }
        float4 hv[16];
        #pragma unroll
        for (int j = 0; j < 16; ++j)
            hv[j] = *(const float4*)(H + (long)ss[j] * 32 + l * 4);
        #pragma unroll
        for (int j = 0; j < 16; ++j) {
            ax += hv[j].x * ww[j]; ay += hv[j].y * ww[j];
            az += hv[j].z * ww[j]; aw += hv[j].w * ww[j];
        }
    }
    for (; e0 + 8 <= end; e0 += 8) {
        int2 ed = eprec[e0 + l];
        int ss[8]; float ww[8];
        #pragma unroll
        for (int j = 0; j < 8; ++j) {
            ss[j] = __shfl(ed.x, j, 8);
            ww[j] = __shfl(__int_as_float(ed.y), j, 8);
        }
        float4 hv[8];
        #pragma unroll
        for (int j = 0; j < 8; ++j)
            hv[j] = *(const float4*)(H + (long)ss[j] * 32 + l * 4);
        #pragma unroll
        for (int j = 0; j < 8; ++j) {
            ax += hv[j].x * ww[j]; ay += hv[j].y * ww[j];
            az += hv[j].z * ww[j]; aw += hv[j].w * ww[j];
        }
    }
    if (e0 < end) {
        int m = end - e0;
        int2 ed = (l < m) ? eprec[e0 + l] : make_int2(0, 0);
        for (int j = 0; j < m; ++j) {
            int s = __shfl(ed.x, j, 8);
            float w = __shfl(__int_as_float(ed.y), j, 8);
            float4 hv = *(const float4*)(H + (long)s * 32 + l * 4);
            ax += hv.x * w; ay += hv.y * w; az += hv.z * w; aw += hv.w * w;
        }
    }
    float sn = snorm[node];
    float4 hv = *(const float4*)(H + (long)node * 32 + l * 4);
    float4 bv = *(const float4*)(bias + l * 4);
    float4 o;
    o.x = tanhf(ax + hv.x * sn + bv.x);
    o.y = tanhf(ay + hv.y * sn + bv.y);
    o.z = tanhf(az + hv.z * sn + bv.z);
    o.w = tanhf(aw + hv.w * sn + bv.w);
    *(float4*)(OUT + (long)node * 32 + l * 4) = o;
}

__global__ void agg1(const float* __restrict__ H4, const int2* __restrict__ eprec,
                     const int* __restrict__ rowptr,
                     const float* __restrict__ snorm, const float* __restrict__ b4,
                     float* __restrict__ X4, int n) {
    int node = blockIdx.x * blockDim.x + threadIdx.x;
    if (node >= n) return;
    int beg = rowptr[node], end = rowptr[node + 1];
    float acc = 0.f;
    for (int e = beg; e < end; ++e) {
        int2 ed = eprec[e];
        acc += H4[ed.x] * __int_as_float(ed.y);
    }
    X4[node] = tanhf(acc + H4[node] * snorm[node] + b4[0]);
}

// ---------------- bitonic sort-256 across one wave (64 lanes x 4 regs) ------------

#define GTP(av,ai,bv,bi) (((av) > (bv)) || ((av) == (bv) && (ai) < (bi)))

__device__ __forceinline__ void bsort256(float& v0, float& v1, float& v2, float& v3,
                                         int& i0, int& i1, int& i2, int& i3, int lane) {
    for (int k = 2; k <= 256; k <<= 1) {
        for (int j = k >> 1; j > 0; j >>= 1) {
            if (j == 64) {
                { bool down = ((lane) & k) == 0;
                  bool agt = GTP(v0, i0, v1, i1);
                  if (down != agt) { float tv = v0; v0 = v1; v1 = tv; int ti = i0; i0 = i1; i1 = ti; } }
                { bool down = ((lane + 128) & k) == 0;
                  bool agt = GTP(v2, i2, v3, i3);
                  if (down != agt) { float tv = v2; v2 = v3; v3 = tv; int ti = i2; i2 = i3; i3 = ti; } }
            } else if (j == 128) {
                { bool down = ((lane) & k) == 0;
                  bool agt = GTP(v0, i0, v2, i2);
                  if (down != agt) { float tv = v0; v0 = v2; v2 = tv; int ti = i0; i0 = i2; i2 = ti; } }
                { bool down = ((lane + 64) & k) == 0;
                  bool agt = GTP(v1, i1, v3, i3);
                  if (down != agt) { float tv = v1; v1 = v3; v3 = tv; int ti = i1; i1 = i3; i3 = ti; } }
            } else {
                #define XSTEP(vv, ii, ebase) { \
                    float ov = __shfl_xor(vv, j, 64); \
                    int   oi = __shfl_xor(ii, j, 64); \
                    bool down = ((lane + (ebase)) & k) == 0; \
                    bool low  = (lane & j) == 0; \
                    bool win  = GTP(vv, ii, ov, oi); \
                    bool keep = (down == low) ? win : !win; \
                    if (!keep) { vv = ov; ii = oi; } }
                XSTEP(v0, i0, 0) XSTEP(v1, i1, 64) XSTEP(v2, i2, 128) XSTEP(v3, i3, 192)
                #undef XSTEP
            }
        }
    }
}

// ---------------- fused topk + head (512 threads / graph) ----------------

__global__ __launch_bounds__(512) void topk_head(
        const float* __restrict__ x1, const float* __restrict__ x2,
        const float* __restrict__ x3, const float* __restrict__ x4,
        const int* __restrict__ gstart,
        const float* __restrict__ w5, const float* __restrict__ b5,
        const float* __restrict__ w6, const float* __restrict__ b6,
        const float* __restrict__ fw1, const float* __restrict__ fb1,
        const float* __restrict__ fw2, const float* __restrict__ fb2,
        float* __restrict__ out) {
    int g = blockIdx.x;
    int t = threadIdx.x;
    __shared__ int topi_l[TOPK];
    __shared__ int selg[TOPK];
    __shared__ float lv[8 * TOPK];
    __shared__ int li[8 * TOPK];
    __shared__ float vals[TKCAP];      // fallback only
    __shared__ float wbv[8];
    __shared__ int wbi[8];
    __shared__ float ws5[16 * 97];
    __shared__ float ws6[32 * 16 * 5];
    __shared__ float wf2[128 * 10];
    __shared__ float part[4][128];
    __shared__ float feats[TOPK][97];
    __shared__ float c5[16][30];
    __shared__ float p6[16][15];
    __shared__ float z[352];
    __shared__ float hh[128];
    __shared__ float oo[10];

    int beg = gstart[g], end = gstart[g + 1];
    int range = end - beg;

    if (range <= 2048) {
        int wv = t >> 6, lane = t & 63;
        int csz = (range + 7) >> 3;
        int cbeg = wv * csz;
        float v0, v1, v2, v3; int j0, j1, j2, j3;
        {
            int id0 = lane, id1 = lane + 64, id2 = lane + 128, id3 = lane + 192;
            bool k0 = (id0 < csz) && (cbeg + id0 < range);
            bool k1 = (id1 < csz) && (cbeg + id1 < range);
            bool k2 = (id2 < csz) && (cbeg + id2 < range);
            bool k3 = (id3 < csz) && (cbeg + id3 < range);
            v0 = k0 ? x4[beg + cbeg + id0] : -INFINITY;
            v1 = k1 ? x4[beg + cbeg + id1] : -INFINITY;
            v2 = k2 ? x4[beg + cbeg + id2] : -INFINITY;
            v3 = k3 ? x4[beg + cbeg + id3] : -INFINITY;
            j0 = k0 ? (cbeg + id0) : (0x0FFFF000 + id0);
            j1 = k1 ? (cbeg + id1) : (0x0FFFF000 + id1);
            j2 = k2 ? (cbeg + id2) : (0x0FFFF000 + id2);
            j3 = k3 ? (cbeg + id3) : (0x0FFFF000 + id3);
        }
        bsort256(v0, v1, v2, v3, j0, j1, j2, j3, lane);
        if (lane < TOPK) { lv[wv * TOPK + lane] = v0; li[wv * TOPK + lane] = j0; }
        __syncthreads();
        if (t < 64) {
            float m0, m1, m2, m3; int n0, n1, n2, n3;
            int id0 = t, id1 = t + 64, id2 = t + 128, id3 = t + 192;
            m0 = (id0 < 8 * TOPK) ? lv[id0] : -INFINITY;
            m1 = (id1 < 8 * TOPK) ? lv[id1] : -INFINITY;
            m2 = (id2 < 8 * TOPK) ? lv[id2] : -INFINITY;
            m3 = (id3 < 8 * TOPK) ? lv[id3] : -INFINITY;
            n0 = (id0 < 8 * TOPK) ? li[id0] : (0x0FFFF000 + id0);
            n1 = (id1 < 8 * TOPK) ? li[id1] : (0x0FFFF000 + id1);
            n2 = (id2 < 8 * TOPK) ? li[id2] : (0x0FFFF000 + id2);
            n3 = (id3 < 8 * TOPK) ? li[id3] : (0x0FFFF000 + id3);
            bsort256(m0, m1, m2, m3, n0, n1, n2, n3, t);
            if (t < TOPK)
                topi_l[t] = (m0 == -INFINITY) ? -1 : beg + n0;
        } else {
            int u = t - 64;   // 448 threads
            for (int i = u; i < 16 * 97; i += 448) ws5[i] = w5[i];
            for (int i = u; i < 32 * 16 * 5; i += 448) ws6[i] = w6[i];
            for (int i = u; i < 128 * 10; i += 448) wf2[i] = fw2[i];
        }
    } else {
        if (t >= 256) {
            int u = t - 256;
            for (int i = u; i < 16 * 97; i += 256) ws5[i] = w5[i];
            for (int i = u; i < 32 * 16 * 5; i += 256) ws6[i] = w6[i];
            for (int i = u; i < 128 * 10; i += 256) wf2[i] = fw2[i];
        }
        int lim = range < TKCAP ? range : TKCAP;
        for (int i = t; i < lim; i += 512) vals[i] = x4[beg + i];
        __syncthreads();
        for (int k = 0; k < TOPK; ++k) {
            float best = -INFINITY;
            int bi = 0x7fffffff;
            for (int i = t; i < lim; i += 512) {
                float v = vals[i];
                if (v > best) { best = v; bi = i; }
            }
            for (int i = TKCAP + t; i < range; i += 512) {
                int gi = beg + i;
                bool taken = false;
                for (int j = 0; j < k; ++j)
                    if (selg[j] == gi) { taken = true; break; }
                if (taken) continue;
                float v = x4[gi];
                if (v > best || (v == best && i < bi)) { best = v; bi = i; }
            }
            #pragma unroll
            for (int off = 1; off < 64; off <<= 1) {
                float ov = __shfl_xor(best, off, 64);
                int oi = __shfl_xor(bi, off, 64);
                if (ov > best || (ov == best && oi < bi)) { best = ov; bi = oi; }
            }
            if ((t & 63) == 0) { wbv[t >> 6] = best; wbi[t >> 6] = bi; }
            __syncthreads();
            if (t == 0) {
                float bv = wbv[0]; int bi0 = wbi[0];
                for (int wq = 1; wq < 8; ++wq)
                    if (wbv[wq] > bv || (wbv[wq] == bv && wbi[wq] < bi0)) { bv = wbv[wq]; bi0 = wbi[wq]; }
                int gl = (bi0 == 0x7fffffff) ? -1 : beg + bi0;
                selg[k] = gl;
                topi_l[k] = gl;
                if (bi0 != 0x7fffffff && bi0 < TKCAP) vals[bi0] = -INFINITY;
            }
            __syncthreads();
        }
    }
    __syncthreads();

    // ---- head (512 threads, weights from LDS) ----
    for (int idx = t; idx < TOPK * 97; idx += 512) {
        int k = idx / 97, j = idx % 97;
        int node = topi_l[k];
        float v = 0.f;
        if (node >= 0) {
            if (j < 32) v = x1[(long)node * 32 + j];
            else if (j < 64) v = x2[(long)node * 32 + (j - 32)];
            else if (j < 96) v = x3[(long)node * 32 + (j - 64)];
            else v = x4[node];
        }
        feats[k][j] = v;
    }
    __syncthreads();

    for (int idx = t; idx < 16 * 30; idx += 512) {
        int oc = idx / 30, k = idx % 30;
        float acc = b5[oc];
        for (int j = 0; j < 97; ++j) acc += ws5[oc * 97 + j] * feats[k][j];
        c5[oc][k] = fmaxf(acc, 0.f);
    }
    __syncthreads();

    for (int idx = t; idx < 16 * 15; idx += 512) {
        int oc = idx / 15, k = idx % 15;
        p6[oc][k] = fmaxf(c5[oc][2 * k], c5[oc][2 * k + 1]);
    }
    __syncthreads();

    for (int idx = t; idx < 32 * 11; idx += 512) {
        int oc = idx / 11, tt = idx % 11;
        float acc = b6[oc];
        for (int ic = 0; ic < 16; ++ic)
            for (int j = 0; j < 5; ++j)
                acc += ws6[(oc * 16 + ic) * 5 + j] * p6[ic][tt + j];
        z[idx] = fmaxf(acc, 0.f);
    }
    __syncthreads();

    {
        int o = t & 127, s = t >> 7;
        float acc = 0.f;
        int i0 = s * 88, i1 = i0 + 88;
        for (int i = i0; i < i1; ++i) acc += z[i] * fw1[i * 128 + o];
        part[s][o] = acc;
    }
    __syncthreads();
    if (t < 128) {
        float v = fb1[t] + ((part[0][t] + part[1][t]) + (part[2][t] + part[3][t]));
        hh[t] = fmaxf(v, 0.f);
    }
    __syncthreads();

    if (t < 10) {
        float acc = fb2[t];
        for (int j = 0; j < 128; ++j) acc += hh[j] * wf2[j * 10 + t];
        oo[t] = acc;
    }
    __syncthreads();

    if (t < 10) {
        float m = -INFINITY;
        for (int c = 0; c < 10; ++c) m = fmaxf(m, oo[c]);
        float s = 0.f;
        for (int c = 0; c < 10; ++c) s += expf(oo[c] - m);
        out[g * 10 + t] = oo[t] - m - logf(s);
    }
}

// ---------------- launch ----------------

extern "C" void kernel_launch(void* const* d_in, const int* in_sizes, int n_in,
                              void* d_out, int out_size, void* d_ws, size_t ws_size,
                              hipStream_t stream) {
    const float* x     = (const float*)d_in[0];
    const int*   ei    = (const int*)d_in[1];
    const int*   batch = (const int*)d_in[2];
    const float* W1 = (const float*)d_in[3];
    const float* b1 = (const float*)d_in[4];
    const float* W2 = (const float*)d_in[5];
    const float* b2 = (const float*)d_in[6];
    const float* W3 = (const float*)d_in[7];
    const float* b3 = (const float*)d_in[8];
    const float* W4 = (const float*)d_in[9];
    const float* b4 = (const float*)d_in[10];
    const float* w5 = (const float*)d_in[11];
    const float* b5 = (const float*)d_in[12];
    const float* w6 = (const float*)d_in[13];
    const float* b6 = (const float*)d_in[14];
    const float* fw1 = (const float*)d_in[15];
    const float* fb1 = (const float*)d_in[16];
    const float* fw2 = (const float*)d_in[17];
    const float* fb2 = (const float*)d_in[18];

    const int N = in_sizes[0] / 128;
    const int E = in_sizes[1] / 2;
    const int* src = ei;
    const int* dst = ei + E;

    char* w = (char*)d_ws;
    size_t off = 0;
    auto alloc = [&](size_t bytes) -> void* {
        void* p = w + off;
        off = (off + bytes + 255) & ~(size_t)255;
        return p;
    };

    // gcur, btot, fcur adjacent -> one memset zeroes all three
    int*   gcur   = (int*)alloc(NBMAX * 4);
    int*   btot   = (int*)alloc(NBMAX * 4);
    int*   fcur   = (int*)alloc(NFMAX * 4);
    int*   bbase  = (int*)alloc(NBMAX * 4);
    int*   gstart = (int*)alloc((size_t)(NGRAPH + 1) * 4);
    int*   rowptr = (int*)alloc((size_t)(N + 1) * 4);
    float* dinv   = (float*)alloc((size_t)N * 4);
    float* snorm  = (float*)alloc((size_t)N * 4);
    int2*  eprec  = (int2*)alloc((size_t)E * 8);
    float* hbuf   = (float*)alloc((size_t)N * 32 * 4);   // aliased as scratch
    float* x1     = (float*)alloc((size_t)N * 32 * 4);   // aliased as scratch2
    float* x2     = (float*)alloc((size_t)N * 32 * 4);
    float* x3     = (float*)alloc((size_t)N * 32 * 4);
    float* h4     = (float*)alloc((size_t)N * 4);
    float* x4     = (float*)alloc((size_t)N * 4);

    int* scratch  = (int*)hbuf;  // packed coarse; live: bin_edges .. bin2
    int* scratch2 = (int*)x1;    // packed fine;   live: bin2 .. scatter_sort

    hipMemsetAsync(gcur, 0, (size_t)(2 * NBMAX + NFMAX) * 4, stream);

    const int NB = (N + (1 << BSHIFT) - 1) >> BSHIFT;
    const int NF = (N + (1 << FSHIFT) - 1) >> FSHIFT;
    const int EB = (E + 2047) / 2048;
    const int GB = (N + TPB - 1) / TPB;

    bhist_gs<<<EB + GB, TPB, 0, stream>>>(src, dst, btot, E, EB, batch, gstart, N, NGRAPH);
    bucket_scan<<<1, NBMAX, 0, stream>>>(btot, bbase, NB);
    bin_edges<<<EB, TPB, 0, stream>>>(src, dst, bbase, gcur, scratch, E);
    bucket_count<<<NB, TPB, 0, stream>>>(scratch, bbase, btot, rowptr, dinv, snorm, N, NB);
    bin2<<<(E + 8191) / 8192, TPB, 0, stream>>>(scratch, bbase, rowptr, fcur, scratch2, N, NB);
    scatter_sort<<<NF, 256, 0, stream>>>(scratch2, rowptr, dinv, eprec, N);

    // layer 1
    mm_128_32<<<(N + 31) / 32, 256, 0, stream>>>(x, W1, hbuf, N);
    agg32<<<((size_t)N * 8 + TPB - 1) / TPB, TPB, 0, stream>>>(hbuf, eprec, rowptr,
                                                               snorm, b1, x1, N);
    // layer 2
    mm_32_32<<<(N + 31) / 32, 256, 0, stream>>>(x1, W2, hbuf, N);
    agg32<<<((size_t)N * 8 + TPB - 1) / TPB, TPB, 0, stream>>>(hbuf, eprec, rowptr,
                                                               snorm, b2, x2, N);
    // layer 3
    mm_32_32<<<(N + 31) / 32, 256, 0, stream>>>(x2, W3, hbuf, N);
    agg32<<<((size_t)N * 8 + TPB - 1) / TPB, TPB, 0, stream>>>(hbuf, eprec, rowptr,
                                                               snorm, b3, x3, N);
    // layer 4
    mm_32_1<<<((size_t)N * 8 + TPB - 1) / TPB, TPB, 0, stream>>>(x3, W4, h4, N);
    agg1<<<(N + TPB - 1) / TPB, TPB, 0, stream>>>(h4, eprec, rowptr, snorm, b4, x4, N);

    // fused topk + head
    topk_head<<<NGRAPH, 512, 0, stream>>>(x1, x2, x3, x4, gstart,
                                          w5, b5, w6, b6, fw1, fb1, fw2, fb2,
                                          (float*)d_out);
}

// Round 17
// 545.415 us; speedup vs baseline: 1.0104x; 1.0104x over previous
//
#include <hip/hip_runtime.h>
#include <math.h>

#define TPB 256
#define TOPK 30
#define NGRAPH 128
#define TKCAP 4096
#define BSHIFT 11
#define NBMAX 128
#define FSHIFT 8
#define NFMAX 800
#define FCAP 4608

// ---------------- CSR build (bucket-based; packed single-int scratch) ----------------
// coarse packed: (src << 11) | (dst & 2047)   [29 bits]
// fine packed:   (src << 8)  | (dst & 255)    [26 bits]

// bhist fused with graph_start (independent work, saves a launch)
__global__ void bhist_gs(const int* __restrict__ src, const int* __restrict__ dst,
                         int* __restrict__ btot, int E, int EB,
                         const int* __restrict__ batch, int* __restrict__ gstart,
                         int n, int B) {
    int blk = blockIdx.x;
    if (blk >= EB) {
        int i = (blk - EB) * blockDim.x + threadIdx.x;
        if (i >= n) return;
        int b = batch[i];
        int bp = (i == 0) ? -1 : batch[i - 1];
        for (int g = bp + 1; g <= b; ++g) gstart[g] = i;
        if (i == n - 1) {
            for (int g = b + 1; g <= B; ++g) gstart[g] = n;
        }
        return;
    }
    __shared__ int bcnt[NBMAX];
    int t = threadIdx.x;
    int base = blk * 2048;
    int lim = E - base; if (lim > 2048) lim = 2048;
    for (int i = t; i < NBMAX; i += 256) bcnt[i] = 0;
    __syncthreads();
    for (int i = t; i < lim; i += 256) {
        int s = src[base + i], d = dst[base + i];
        if (s != d) atomicAdd(&bcnt[d >> BSHIFT], 1);
    }
    __syncthreads();
    for (int i = t; i < NBMAX; i += 256)
        if (bcnt[i] > 0) atomicAdd(&btot[i], bcnt[i]);
}

// LDS exclusive scan of btot into sb[] (NB <= NBMAX <= blockDim)
#define SCAN_BTOT(sb, btot, NB, t)                                  \
    {                                                               \
        int vv_ = 0;                                                \
        if ((t) < NBMAX) { vv_ = ((t) < (NB)) ? (btot)[t] : 0; (sb)[t] = vv_; } \
        __syncthreads();                                            \
        for (int o_ = 1; o_ < NBMAX; o_ <<= 1) {                    \
            int x_ = 0;                                             \
            if ((t) < NBMAX && (t) >= o_) x_ = (sb)[(t) - o_];      \
            __syncthreads();                                        \
            if ((t) < NBMAX) (sb)[t] += x_;                         \
            __syncthreads();                                        \
        }                                                           \
        if ((t) < NBMAX) (sb)[t] -= vv_;                            \
        __syncthreads();                                            \
    }

__global__ void bin_edges(const int* __restrict__ src, const int* __restrict__ dst,
                          const int* __restrict__ btot, int* __restrict__ gcur,
                          int* __restrict__ scratch, int E, int NB) {
    __shared__ int eds[2048];
    __shared__ unsigned char ebk[2048];
    __shared__ int sbase[NBMAX];
    __shared__ int bcnt[NBMAX], bbase[NBMAX], boff[NBMAX];
    int t = threadIdx.x;
    SCAN_BTOT(sbase, btot, NB, t);
    int base = blockIdx.x * 2048;
    int lim = E - base; if (lim > 2048) lim = 2048;
    for (int i = t; i < NBMAX; i += 256) { bcnt[i] = 0; boff[i] = 0; }
    __syncthreads();
    for (int i = t; i < lim; i += 256) {
        int s = src[base + i], d = dst[base + i];
        if (s == d) { ebk[i] = 255; }
        else {
            int b = d >> BSHIFT;
            ebk[i] = (unsigned char)b;
            eds[i] = (s << BSHIFT) | (d & ((1 << BSHIFT) - 1));
            atomicAdd(&bcnt[b], 1);
        }
    }
    __syncthreads();
    for (int i = t; i < NBMAX; i += 256) {
        if (bcnt[i] > 0)
            bbase[i] = sbase[i] + atomicAdd(&gcur[i], bcnt[i]);
    }
    __syncthreads();
    for (int i = t; i < lim; i += 256) {
        if (ebk[i] != 255) {
            int b = ebk[i];
            int pos = bbase[b] + atomicAdd(&boff[b], 1);
            scratch[pos] = eds[i];
        }
    }
}

// per-node hist over the bucket span -> dinv/snorm AND rowptr (LDS blocked scan).
__global__ void bucket_count(const int* __restrict__ scratch,
                             const int* __restrict__ btot,
                             int* __restrict__ rowptr, float* __restrict__ dinv,
                             float* __restrict__ snorm, int N, int NB) {
    __shared__ int sbase[NBMAX];
    __shared__ int hist[1 << BSHIFT];
    __shared__ int ls2[256];
    int b = blockIdx.x, t = threadIdx.x;
    SCAN_BTOT(sbase, btot, NB, t);
    int nlo = b << BSHIFT;
    int nn = N - nlo; if (nn > (1 << BSHIFT)) nn = 1 << BSHIFT;
    for (int i = t; i < (1 << BSHIFT); i += 256) hist[i] = 0;
    __syncthreads();
    int lo = sbase[b], hi = lo + btot[b];
    for (int e = lo + t; e < hi; e += 256)
        atomicAdd(&hist[scratch[e] & ((1 << BSHIFT) - 1)], 1);
    __syncthreads();
    int loc[8]; int run = 0;
    #pragma unroll
    for (int j = 0; j < 8; ++j) { loc[j] = run; run += hist[t * 8 + j]; }
    ls2[t] = run;
    __syncthreads();
    for (int o = 1; o < 256; o <<= 1) {
        int x = (t >= o) ? ls2[t - o] : 0;
        __syncthreads();
        ls2[t] += x;
        __syncthreads();
    }
    int base = sbase[b] + ls2[t] - run;
    #pragma unroll
    for (int j = 0; j < 8; ++j) {
        int i = t * 8 + j;
        if (i < nn) {
            rowptr[nlo + i] = base + loc[j];
            int c = hist[i];
            float deg = (float)c + 1.0f;
            dinv[nlo + i] = 1.0f / sqrtf(deg);
            snorm[nlo + i] = 1.0f / deg;
        }
    }
    if (b == NB - 1 && t == 0) rowptr[N] = sbase[b] + btot[b];
}

// re-bin coarse-major scratch -> fine-major scratch2 (both packed single int).
__global__ void bin2(const int* __restrict__ scratch, const int* __restrict__ btot,
                     const int* __restrict__ rowptr,
                     int* __restrict__ fcur, int* __restrict__ scratch2, int N, int NB) {
    __shared__ int bb[NBMAX];
    __shared__ int fcnt[NFMAX], fbase[NFMAX], foff[NFMAX];
    __shared__ unsigned short fid[8192];
    int t = threadIdx.x;
    SCAN_BTOT(bb, btot, NB, t);
    if (t < NBMAX && t >= NB) bb[t] = 0x7fffffff;
    int En = rowptr[N];
    int base = blockIdx.x * 8192;
    if (base >= En) return;
    int lim = En - base; if (lim > 8192) lim = 8192;
    for (int i = t; i < NFMAX; i += 256) { fcnt[i] = 0; foff[i] = 0; }
    __syncthreads();
    for (int i = t; i < lim; i += 256) {
        int gi = base + i;
        int lo = 0, hi = NB - 1;
        while (lo < hi) { int m = (lo + hi + 1) >> 1; if (bb[m] <= gi) lo = m; else hi = m - 1; }
        int e = scratch[gi];
        int fi = (lo << (BSHIFT - FSHIFT)) | ((e >> FSHIFT) & ((1 << (BSHIFT - FSHIFT)) - 1));
        fid[i] = (unsigned short)fi;
        atomicAdd(&fcnt[fi], 1);
    }
    __syncthreads();
    for (int fi = t; fi < NFMAX; fi += 256) {
        if (fcnt[fi] > 0)
            fbase[fi] = rowptr[fi << FSHIFT] + atomicAdd(&fcur[fi], fcnt[fi]);
    }
    __syncthreads();
    for (int i = t; i < lim; i += 256) {
        int e = scratch[base + i];
        int fi = fid[i];
        int pf = ((e >> BSHIFT) << FSHIFT) | (e & ((1 << FSHIFT) - 1));
        int pos = fbase[fi] + atomicAdd(&foff[fi], 1);
        scratch2[pos] = pf;
    }
}

// per fine bucket: LDS counting sort of its own span -> fully coalesced eprec writes.
__global__ __launch_bounds__(256) void scatter_sort(const int* __restrict__ scratch2,
                                                    const int* __restrict__ rowptr,
                                                    const float* __restrict__ dinv,
                                                    int2* __restrict__ eprec, int N) {
    __shared__ int pA[FCAP], inv[FCAP];
    __shared__ int hist[1 << FSHIFT];
    __shared__ int hcur[1 << FSHIFT];
    int f = blockIdx.x, t = threadIdx.x;
    int nlo = f << FSHIFT;
    int nhi = nlo + (1 << FSHIFT); if (nhi > N) nhi = N;
    int lo = rowptr[nlo], hi = rowptr[nhi];
    int span = hi - lo;
    hist[t] = 0;
    __syncthreads();
    if (span <= FCAP) {
        for (int i = t; i < span; i += 256) {
            int e = scratch2[lo + i];
            pA[i] = e;
            atomicAdd(&hist[e & 255], 1);
        }
        __syncthreads();
        int v = hist[t];
        hcur[t] = v;
        __syncthreads();
        for (int o = 1; o < 256; o <<= 1) {
            int x = (t >= o) ? hcur[t - o] : 0;
            __syncthreads();
            hcur[t] += x;
            __syncthreads();
        }
        int excl = hcur[t] - v;
        __syncthreads();
        hcur[t] = excl;
        __syncthreads();
        for (int i = t; i < span; i += 256) {
            int slot = atomicAdd(&hcur[pA[i] & 255], 1);
            inv[slot] = i;
        }
        __syncthreads();
        for (int p = t; p < span; p += 256) {
            int e = pA[inv[p]];
            int s = e >> FSHIFT, d = nlo | (e & 255);
            eprec[lo + p] = make_int2(s, __float_as_int(dinv[s] * dinv[d]));
        }
    } else {
        for (int e0 = lo + t; e0 < hi; e0 += 256) {
            int e = scratch2[e0];
            int s = e >> FSHIFT, d = nlo | (e & 255);
            int p = rowptr[d] + atomicAdd(&hist[e & 255], 1);
            eprec[p] = make_int2(s, __float_as_int(dinv[s] * dinv[d]));
        }
    }
}

// ---------------- GEMMs (register-tiled: 4 cols/thread, b128 LDS reads) ----------------

__global__ void mm_128_32(const float* __restrict__ X, const float* __restrict__ W,
                          float* __restrict__ H, int n) {
    __shared__ float Ws[128 * 32];
    __shared__ float xs[32 * 128];
    int t = threadIdx.x;
    int rbase = blockIdx.x * 32;
    #pragma unroll
    for (int j = 0; j < 4; ++j) {
        int idx = t + 256 * j;
        *(float4*)(Ws + idx * 4) = *(const float4*)(W + idx * 4);
        int row = rbase + (idx >> 5);
        float4 v = make_float4(0.f, 0.f, 0.f, 0.f);
        if (row < n) v = *(const float4*)(X + (long)rbase * 128 + idx * 4);
        *(float4*)(xs + idx * 4) = v;
    }
    __syncthreads();
    int c4 = (t & 7) * 4, r = t >> 3;
    int row = rbase + r;
    if (row >= n) return;
    float ac0 = 0.f, ac1 = 0.f, ac2 = 0.f, ac3 = 0.f;
    #pragma unroll 8
    for (int k0 = 0; k0 < 128; k0 += 4) {
        float4 xv = *(const float4*)(xs + r * 128 + k0);
        #pragma unroll
        for (int j = 0; j < 4; ++j) {
            float xj = (j == 0) ? xv.x : (j == 1) ? xv.y : (j == 2) ? xv.z : xv.w;
            float4 wv = *(const float4*)(Ws + (k0 + j) * 32 + c4);
            ac0 += xj * wv.x; ac1 += xj * wv.y; ac2 += xj * wv.z; ac3 += xj * wv.w;
        }
    }
    *(float4*)(H + (long)row * 32 + c4) = make_float4(ac0, ac1, ac2, ac3);
}

__global__ void mm_32_32(const float* __restrict__ X, const float* __restrict__ W,
                         float* __restrict__ H, int n) {
    __shared__ float Ws[32 * 32];
    __shared__ float xs[32 * 32];
    int t = threadIdx.x;
    int rbase = blockIdx.x * 32;
    {
        *(float4*)(Ws + t * 4) = *(const float4*)(W + t * 4);
        int row = rbase + (t >> 3);
        float4 v = make_float4(0.f, 0.f, 0.f, 0.f);
        if (row < n) v = *(const float4*)(X + (long)rbase * 32 + t * 4);
        *(float4*)(xs + t * 4) = v;
    }
    __syncthreads();
    int c4 = (t & 7) * 4, r = t >> 3;
    int row = rbase + r;
    if (row >= n) return;
    float ac0 = 0.f, ac1 = 0.f, ac2 = 0.f, ac3 = 0.f;
    #pragma unroll
    for (int k0 = 0; k0 < 32; k0 += 4) {
        float4 xv = *(const float4*)(xs + r * 32 + k0);
        #pragma unroll
        for (int j = 0; j < 4; ++j) {
            float xj = (j == 0) ? xv.x : (j == 1) ? xv.y : (j == 2) ? xv.z : xv.w;
            float4 wv = *(const float4*)(Ws + (k0 + j) * 32 + c4);
            ac0 += xj * wv.x; ac1 += xj * wv.y; ac2 += xj * wv.z; ac3 += xj * wv.w;
        }
    }
    *(float4*)(H + (long)row * 32 + c4) = make_float4(ac0, ac1, ac2, ac3);
}

__global__ void mm_32_1(const float* __restrict__ X, const float* __restrict__ W,
                        float* __restrict__ H4, int n) {
    int gid = blockIdx.x * blockDim.x + threadIdx.x;
    int node = gid >> 3, l = gid & 7;
    if (node >= n) return;
    float4 v = *(const float4*)(X + (long)node * 32 + l * 4);
    float s = v.x * W[l * 4] + v.y * W[l * 4 + 1] + v.z * W[l * 4 + 2] + v.w * W[l * 4 + 3];
    s += __shfl_xor(s, 1, 64);
    s += __shfl_xor(s, 2, 64);
    s += __shfl_xor(s, 4, 64);
    if (l == 0) H4[node] = s;
}

// ---------------- edge aggregation (gather, 8-deep — measured optimum) ----------------

__global__ void agg32(const float* __restrict__ H, const int2* __restrict__ eprec,
                      const int* __restrict__ rowptr,
                      const float* __restrict__ snorm, const float* __restrict__ bias,
                      float* __restrict__ OUT, int n) {
    int gid = blockIdx.x * blockDim.x + threadIdx.x;
    int node = gid >> 3, l = gid & 7;
    if (node >= n) return;
    int beg = rowptr[node], end = rowptr[node + 1];
    float ax = 0.f, ay = 0.f, az = 0.f, aw = 0.f;
    int e0 = beg;
    for (; e0 + 8 <= end; e0 += 8) {
        int2 ed = eprec[e0 + l];
        int ss[8]; float ww[8];
        #pragma unroll
        for (int j = 0; j < 8; ++j) {
            ss[j] = __shfl(ed.x, j, 8);
            ww[j] = __shfl(__int_as_float(ed.y), j, 8);
        }
        float4 hv[8];
        #pragma unroll
        for (int j = 0; j < 8; ++j)
            hv[j] = *(const float4*)(H + (long)ss[j] * 32 + l * 4);
        #pragma unroll
        for (int j = 0; j < 8; ++j) {
            ax += hv[j].x * ww[j]; ay += hv[j].y * ww[j];
            az += hv[j].z * ww[j]; aw += hv[j].w * ww[j];
        }
    }
    if (e0 < end) {
        int m = end - e0;
        int2 ed = (l < m) ? eprec[e0 + l] : make_int2(0, 0);
        for (int j = 0; j < m; ++j) {
            int s = __shfl(ed.x, j, 8);
            float w = __shfl(__int_as_float(ed.y), j, 8);
            float4 hv = *(const float4*)(H + (long)s * 32 + l * 4);
            ax += hv.x * w; ay += hv.y * w; az += hv.z * w; aw += hv.w * w;
        }
    }
    float sn = snorm[node];
    float4 hv = *(const float4*)(H + (long)node * 32 + l * 4);
    float4 bv = *(const float4*)(bias + l * 4);
    float4 o;
    o.x = tanhf(ax + hv.x * sn + bv.x);
    o.y = tanhf(ay + hv.y * sn + bv.y);
    o.z = tanhf(az + hv.z * sn + bv.z);
    o.w = tanhf(aw + hv.w * sn + bv.w);
    *(float4*)(OUT + (long)node * 32 + l * 4) = o;
}

__global__ void agg1(const float* __restrict__ H4, const int2* __restrict__ eprec,
                     const int* __restrict__ rowptr,
                     const float* __restrict__ snorm, const float* __restrict__ b4,
                     float* __restrict__ X4, int n) {
    int node = blockIdx.x * blockDim.x + threadIdx.x;
    if (node >= n) return;
    int beg = rowptr[node], end = rowptr[node + 1];
    float acc = 0.f;
    for (int e = beg; e < end; ++e) {
        int2 ed = eprec[e];
        acc += H4[ed.x] * __int_as_float(ed.y);
    }
    X4[node] = tanhf(acc + H4[node] * snorm[node] + b4[0]);
}

// ---------------- bitonic sort-256 across one wave (64 lanes x 4 regs) ------------

#define GTP(av,ai,bv,bi) (((av) > (bv)) || ((av) == (bv) && (ai) < (bi)))

__device__ __forceinline__ void bsort256(float& v0, float& v1, float& v2, float& v3,
                                         int& i0, int& i1, int& i2, int& i3, int lane) {
    for (int k = 2; k <= 256; k <<= 1) {
        for (int j = k >> 1; j > 0; j >>= 1) {
            if (j == 64) {
                { bool down = ((lane) & k) == 0;
                  bool agt = GTP(v0, i0, v1, i1);
                  if (down != agt) { float tv = v0; v0 = v1; v1 = tv; int ti = i0; i0 = i1; i1 = ti; } }
                { bool down = ((lane + 128) & k) == 0;
                  bool agt = GTP(v2, i2, v3, i3);
                  if (down != agt) { float tv = v2; v2 = v3; v3 = tv; int ti = i2; i2 = i3; i3 = ti; } }
            } else if (j == 128) {
                { bool down = ((lane) & k) == 0;
                  bool agt = GTP(v0, i0, v2, i2);
                  if (down != agt) { float tv = v0; v0 = v2; v2 = tv; int ti = i0; i0 = i2; i2 = ti; } }
                { bool down = ((lane + 64) & k) == 0;
                  bool agt = GTP(v1, i1, v3, i3);
                  if (down != agt) { float tv = v1; v1 = v3; v3 = tv; int ti = i1; i1 = i3; i3 = ti; } }
            } else {
                #define XSTEP(vv, ii, ebase) { \
                    float ov = __shfl_xor(vv, j, 64); \
                    int   oi = __shfl_xor(ii, j, 64); \
                    bool down = ((lane + (ebase)) & k) == 0; \
                    bool low  = (lane & j) == 0; \
                    bool win  = GTP(vv, ii, ov, oi); \
                    bool keep = (down == low) ? win : !win; \
                    if (!keep) { vv = ov; ii = oi; } }
                XSTEP(v0, i0, 0) XSTEP(v1, i1, 64) XSTEP(v2, i2, 128) XSTEP(v3, i3, 192)
                #undef XSTEP
            }
        }
    }
}

// ---------------- fused topk + head (512 threads / graph) ----------------

__global__ __launch_bounds__(512) void topk_head(
        const float* __restrict__ x1, const float* __restrict__ x2,
        const float* __restrict__ x3, const float* __restrict__ x4,
        const int* __restrict__ gstart,
        const float* __restrict__ w5, const float* __restrict__ b5,
        const float* __restrict__ w6, const float* __restrict__ b6,
        const float* __restrict__ fw1, const float* __restrict__ fb1,
        const float* __restrict__ fw2, const float* __restrict__ fb2,
        float* __restrict__ out) {
    int g = blockIdx.x;
    int t = threadIdx.x;
    __shared__ int topi_l[TOPK];
    __shared__ int selg[TOPK];
    __shared__ float lv[8 * TOPK];
    __shared__ int li[8 * TOPK];
    __shared__ float vals[TKCAP];      // fallback only
    __shared__ float wbv[8];
    __shared__ int wbi[8];
    __shared__ float ws5[16 * 97];
    __shared__ float ws6[32 * 16 * 5];
    __shared__ float wf2[128 * 10];
    __shared__ float part[4][128];
    __shared__ float feats[TOPK][97];
    __shared__ float c5[16][30];
    __shared__ float p6[16][15];
    __shared__ float z[352];
    __shared__ float hh[128];
    __shared__ float oo[10];

    int beg = gstart[g], end = gstart[g + 1];
    int range = end - beg;

    if (range <= 2048) {
        int wv = t >> 6, lane = t & 63;
        int csz = (range + 7) >> 3;
        int cbeg = wv * csz;
        float v0, v1, v2, v3; int j0, j1, j2, j3;
        {
            int id0 = lane, id1 = lane + 64, id2 = lane + 128, id3 = lane + 192;
            bool k0 = (id0 < csz) && (cbeg + id0 < range);
            bool k1 = (id1 < csz) && (cbeg + id1 < range);
            bool k2 = (id2 < csz) && (cbeg + id2 < range);
            bool k3 = (id3 < csz) && (cbeg + id3 < range);
            v0 = k0 ? x4[beg + cbeg + id0] : -INFINITY;
            v1 = k1 ? x4[beg + cbeg + id1] : -INFINITY;
            v2 = k2 ? x4[beg + cbeg + id2] : -INFINITY;
            v3 = k3 ? x4[beg + cbeg + id3] : -INFINITY;
            j0 = k0 ? (cbeg + id0) : (0x0FFFF000 + id0);
            j1 = k1 ? (cbeg + id1) : (0x0FFFF000 + id1);
            j2 = k2 ? (cbeg + id2) : (0x0FFFF000 + id2);
            j3 = k3 ? (cbeg + id3) : (0x0FFFF000 + id3);
        }
        bsort256(v0, v1, v2, v3, j0, j1, j2, j3, lane);
        if (lane < TOPK) { lv[wv * TOPK + lane] = v0; li[wv * TOPK + lane] = j0; }
        __syncthreads();
        if (t < 64) {
            float m0, m1, m2, m3; int n0, n1, n2, n3;
            int id0 = t, id1 = t + 64, id2 = t + 128, id3 = t + 192;
            m0 = (id0 < 8 * TOPK) ? lv[id0] : -INFINITY;
            m1 = (id1 < 8 * TOPK) ? lv[id1] : -INFINITY;
            m2 = (id2 < 8 * TOPK) ? lv[id2] : -INFINITY;
            m3 = (id3 < 8 * TOPK) ? lv[id3] : -INFINITY;
            n0 = (id0 < 8 * TOPK) ? li[id0] : (0x0FFFF000 + id0);
            n1 = (id1 < 8 * TOPK) ? li[id1] : (0x0FFFF000 + id1);
            n2 = (id2 < 8 * TOPK) ? li[id2] : (0x0FFFF000 + id2);
            n3 = (id3 < 8 * TOPK) ? li[id3] : (0x0FFFF000 + id3);
            bsort256(m0, m1, m2, m3, n0, n1, n2, n3, t);
            if (t < TOPK)
                topi_l[t] = (m0 == -INFINITY) ? -1 : beg + n0;
        } else {
            int u = t - 64;   // 448 threads
            for (int i = u; i < 16 * 97; i += 448) ws5[i] = w5[i];
            for (int i = u; i < 32 * 16 * 5; i += 448) ws6[i] = w6[i];
            for (int i = u; i < 128 * 10; i += 448) wf2[i] = fw2[i];
        }
    } else {
        if (t >= 256) {
            int u = t - 256;
            for (int i = u; i < 16 * 97; i += 256) ws5[i] = w5[i];
            for (int i = u; i < 32 * 16 * 5; i += 256) ws6[i] = w6[i];
            for (int i = u; i < 128 * 10; i += 256) wf2[i] = fw2[i];
        }
        int lim = range < TKCAP ? range : TKCAP;
        for (int i = t; i < lim; i += 512) vals[i] = x4[beg + i];
        __syncthreads();
        for (int k = 0; k < TOPK; ++k) {
            float best = -INFINITY;
            int bi = 0x7fffffff;
            for (int i = t; i < lim; i += 512) {
                float v = vals[i];
                if (v > best) { best = v; bi = i; }
            }
            for (int i = TKCAP + t; i < range; i += 512) {
                int gi = beg + i;
                bool taken = false;
                for (int j = 0; j < k; ++j)
                    if (selg[j] == gi) { taken = true; break; }
                if (taken) continue;
                float v = x4[gi];
                if (v > best || (v == best && i < bi)) { best = v; bi = i; }
            }
            #pragma unroll
            for (int off = 1; off < 64; off <<= 1) {
                float ov = __shfl_xor(best, off, 64);
                int oi = __shfl_xor(bi, off, 64);
                if (ov > best || (ov == best && oi < bi)) { best = ov; bi = oi; }
            }
            if ((t & 63) == 0) { wbv[t >> 6] = best; wbi[t >> 6] = bi; }
            __syncthreads();
            if (t == 0) {
                float bv = wbv[0]; int bi0 = wbi[0];
                for (int wq = 1; wq < 8; ++wq)
                    if (wbv[wq] > bv || (wbv[wq] == bv && wbi[wq] < bi0)) { bv = wbv[wq]; bi0 = wbi[wq]; }
                int gl = (bi0 == 0x7fffffff) ? -1 : beg + bi0;
                selg[k] = gl;
                topi_l[k] = gl;
                if (bi0 != 0x7fffffff && bi0 < TKCAP) vals[bi0] = -INFINITY;
            }
            __syncthreads();
        }
    }
    __syncthreads();

    // ---- head (512 threads, weights from LDS) ----
    for (int idx = t; idx < TOPK * 97; idx += 512) {
        int k = idx / 97, j = idx % 97;
        int node = topi_l[k];
        float v = 0.f;
        if (node >= 0) {
            if (j < 32) v = x1[(long)node * 32 + j];
            else if (j < 64) v = x2[(long)node * 32 + (j - 32)];
            else if (j < 96) v = x3[(long)node * 32 + (j - 64)];
            else v = x4[node];
        }
        feats[k][j] = v;
    }
    __syncthreads();

    for (int idx = t; idx < 16 * 30; idx += 512) {
        int oc = idx / 30, k = idx % 30;
        float acc = b5[oc];
        for (int j = 0; j < 97; ++j) acc += ws5[oc * 97 + j] * feats[k][j];
        c5[oc][k] = fmaxf(acc, 0.f);
    }
    __syncthreads();

    for (int idx = t; idx < 16 * 15; idx += 512) {
        int oc = idx / 15, k = idx % 15;
        p6[oc][k] = fmaxf(c5[oc][2 * k], c5[oc][2 * k + 1]);
    }
    __syncthreads();

    for (int idx = t; idx < 32 * 11; idx += 512) {
        int oc = idx / 11, tt = idx % 11;
        float acc = b6[oc];
        for (int ic = 0; ic < 16; ++ic)
            for (int j = 0; j < 5; ++j)
                acc += ws6[(oc * 16 + ic) * 5 + j] * p6[ic][tt + j];
        z[idx] = fmaxf(acc, 0.f);
    }
    __syncthreads();

    {
        int o = t & 127, s = t >> 7;
        float acc = 0.f;
        int i0 = s * 88, i1 = i0 + 88;
        for (int i = i0; i < i1; ++i) acc += z[i] * fw1[i * 128 + o];
        part[s][o] = acc;
    }
    __syncthreads();
    if (t < 128) {
        float v = fb1[t] + ((part[0][t] + part[1][t]) + (part[2][t] + part[3][t]));
        hh[t] = fmaxf(v, 0.f);
    }
    __syncthreads();

    if (t < 10) {
        float acc = fb2[t];
        for (int j = 0; j < 128; ++j) acc += hh[j] * wf2[j * 10 + t];
        oo[t] = acc;
    }
    __syncthreads();

    if (t < 10) {
        float m = -INFINITY;
        for (int c = 0; c < 10; ++c) m = fmaxf(m, oo[c]);
        float s = 0.f;
        for (int c = 0; c < 10; ++c) s += expf(oo[c] - m);
        out[g * 10 + t] = oo[t] - m - logf(s);
    }
}

// ---------------- launch ----------------

extern "C" void kernel_launch(void* const* d_in, const int* in_sizes, int n_in,
                              void* d_out, int out_size, void* d_ws, size_t ws_size,
                              hipStream_t stream) {
    const float* x     = (const float*)d_in[0];
    const int*   ei    = (const int*)d_in[1];
    const int*   batch = (const int*)d_in[2];
    const float* W1 = (const float*)d_in[3];
    const float* b1 = (const float*)d_in[4];
    const float* W2 = (const float*)d_in[5];
    const float* b2 = (const float*)d_in[6];
    const float* W3 = (const float*)d_in[7];
    const float* b3 = (const float*)d_in[8];
    const float* W4 = (const float*)d_in[9];
    const float* b4 = (const float*)d_in[10];
    const float* w5 = (const float*)d_in[11];
    const float* b5 = (const float*)d_in[12];
    const float* w6 = (const float*)d_in[13];
    const float* b6 = (const float*)d_in[14];
    const float* fw1 = (const float*)d_in[15];
    const float* fb1 = (const float*)d_in[16];
    const float* fw2 = (const float*)d_in[17];
    const float* fb2 = (const float*)d_in[18];

    const int N = in_sizes[0] / 128;
    const int E = in_sizes[1] / 2;
    const int* src = ei;
    const int* dst = ei + E;

    char* w = (char*)d_ws;
    size_t off = 0;
    auto alloc = [&](size_t bytes) -> void* {
        void* p = w + off;
        off = (off + bytes + 255) & ~(size_t)255;
        return p;
    };

    // gcur, btot, fcur adjacent -> one memset zeroes all three
    int*   gcur   = (int*)alloc(NBMAX * 4);
    int*   btot   = (int*)alloc(NBMAX * 4);
    int*   fcur   = (int*)alloc(NFMAX * 4);
    int*   gstart = (int*)alloc((size_t)(NGRAPH + 1) * 4);
    int*   rowptr = (int*)alloc((size_t)(N + 1) * 4);
    float* dinv   = (float*)alloc((size_t)N * 4);
    float* snorm  = (float*)alloc((size_t)N * 4);
    int2*  eprec  = (int2*)alloc((size_t)E * 8);
    float* hbuf   = (float*)alloc((size_t)N * 32 * 4);   // aliased as scratch
    float* x1     = (float*)alloc((size_t)N * 32 * 4);   // aliased as scratch2
    float* x2     = (float*)alloc((size_t)N * 32 * 4);
    float* x3     = (float*)alloc((size_t)N * 32 * 4);
    float* h4     = (float*)alloc((size_t)N * 4);
    float* x4     = (float*)alloc((size_t)N * 4);

    int* scratch  = (int*)hbuf;  // packed coarse; live: bin_edges .. bin2
    int* scratch2 = (int*)x1;    // packed fine;   live: bin2 .. scatter_sort

    hipMemsetAsync(gcur, 0, (size_t)(2 * NBMAX + NFMAX) * 4, stream);

    const int NB = (N + (1 << BSHIFT) - 1) >> BSHIFT;
    const int NF = (N + (1 << FSHIFT) - 1) >> FSHIFT;
    const int EB = (E + 2047) / 2048;
    const int GB = (N + TPB - 1) / TPB;

    bhist_gs<<<EB + GB, TPB, 0, stream>>>(src, dst, btot, E, EB, batch, gstart, N, NGRAPH);
    bin_edges<<<EB, TPB, 0, stream>>>(src, dst, btot, gcur, scratch, E, NB);
    bucket_count<<<NB, TPB, 0, stream>>>(scratch, btot, rowptr, dinv, snorm, N, NB);
    bin2<<<(E + 8191) / 8192, TPB, 0, stream>>>(scratch, btot, rowptr, fcur, scratch2, N, NB);
    scatter_sort<<<NF, 256, 0, stream>>>(scratch2, rowptr, dinv, eprec, N);

    // layer 1
    mm_128_32<<<(N + 31) / 32, 256, 0, stream>>>(x, W1, hbuf, N);
    agg32<<<((size_t)N * 8 + TPB - 1) / TPB, TPB, 0, stream>>>(hbuf, eprec, rowptr,
                                                               snorm, b1, x1, N);
    // layer 2
    mm_32_32<<<(N + 31) / 32, 256, 0, stream>>>(x1, W2, hbuf, N);
    agg32<<<((size_t)N * 8 + TPB - 1) / TPB, TPB, 0, stream>>>(hbuf, eprec, rowptr,
                                                               snorm, b2, x2, N);
    // layer 3
    mm_32_32<<<(N + 31) / 32, 256, 0, stream>>>(x2, W3, hbuf, N);
    agg32<<<((size_t)N * 8 + TPB - 1) / TPB, TPB, 0, stream>>>(hbuf, eprec, rowptr,
                                                               snorm, b3, x3, N);
    // layer 4
    mm_32_1<<<((size_t)N * 8 + TPB - 1) / TPB, TPB, 0, stream>>>(x3, W4, h4, N);
    agg1<<<(N + TPB - 1) / TPB, TPB, 0, stream>>>(h4, eprec, rowptr, snorm, b4, x4, N);

    // fused topk + head
    topk_head<<<NGRAPH, 512, 0, stream>>>(x1, x2, x3, x4, gstart,
                                          w5, b5, w6, b6, fw1, fb1, fw2, fb2,
                                          (float*)d_out);
}